// Round 1
// baseline (272.813 us; speedup 1.0000x reference)
//
#include <hip/hip_runtime.h>

#define NPAIR 625   // T*T = 25*25
#define GMAX  512   // n_graphs in setup_inputs
#define BLK   256

__global__ void zero_out_kernel(float* __restrict__ out, int n) {
    int i = blockIdx.x * blockDim.x + threadIdx.x;
    if (i < n) out[i] = 0.0f;
}

__global__ __launch_bounds__(BLK) void poly_seg_kernel(
    const float* __restrict__ pos,        // (N,3)
    const float* __restrict__ ks,         // (4,25,25)
    const float* __restrict__ v0,         // (25,25)
    const int*   __restrict__ map0,       // (E,)
    const int*   __restrict__ map1,       // (E,)
    const int*   __restrict__ atype,      // (N,)
    const int*   __restrict__ mbatch,     // (E,) sorted
    float*       __restrict__ out,        // (G,)
    int E, int chunk)
{
    __shared__ float4 s_k[NPAIR];   // (k0,k1,k2,k3) per type-pair
    __shared__ float  s_v0[NPAIR];
    __shared__ float  s_acc[GMAX];

    const int tid = threadIdx.x;

    // Stage coefficient tables into LDS
    for (int i = tid; i < NPAIR; i += BLK) {
        s_k[i]  = make_float4(ks[i], ks[NPAIR + i], ks[2*NPAIR + i], ks[3*NPAIR + i]);
        s_v0[i] = v0[i];
    }
    for (int i = tid; i < GMAX; i += BLK) s_acc[i] = 0.0f;

    const long long cs64 = (long long)blockIdx.x * (long long)chunk;
    if (cs64 >= (long long)E) return;   // block-uniform; safe before barrier
    const int chunk_start = (int)cs64;
    const int chunk_end   = min(chunk_start + chunk, E);

    __syncthreads();

    // Per-thread register accumulation; mapping_batch sorted -> bucket rarely changes
    float acc = 0.0f;
    int   gcur = -1;
    for (int e = chunk_start + tid; e < chunk_end; e += BLK) {
        const int i0 = map0[e];
        const int i1 = map1[e];
        const int g  = mbatch[e];

        const float dx = pos[i0*3 + 0] - pos[i1*3 + 0];
        const float dy = pos[i0*3 + 1] - pos[i1*3 + 1];
        const float dz = pos[i0*3 + 2] - pos[i1*3 + 2];
        const float x  = sqrtf(dx*dx + dy*dy + dz*dz);

        const int pair = atype[i0] * 25 + atype[i1];
        const float4 k = s_k[pair];
        // V = v0 + k0*x + k1*x^2 + k2*x^3 + k3*x^4  (Horner)
        const float V = s_v0[pair] + x*(k.x + x*(k.y + x*(k.z + x*k.w)));

        if (g != gcur) {
            if (gcur >= 0) atomicAdd(&s_acc[gcur], acc);
            gcur = g;
            acc  = 0.0f;
        }
        acc += V;
    }
    if (gcur >= 0) atomicAdd(&s_acc[gcur], acc);

    __syncthreads();

    // Sorted batch => this block only touched buckets [blo, bhi]
    const int blo = mbatch[chunk_start];
    const int bhi = mbatch[chunk_end - 1];
    for (int i = blo + tid; i <= bhi; i += BLK) {
        atomicAdd(&out[i], s_acc[i]);
    }
}

extern "C" void kernel_launch(void* const* d_in, const int* in_sizes, int n_in,
                              void* d_out, int out_size, void* d_ws, size_t ws_size,
                              hipStream_t stream) {
    const float* pos    = (const float*)d_in[0];
    const float* ks     = (const float*)d_in[1];
    const float* v0     = (const float*)d_in[2];
    const int*   map    = (const int*)d_in[3];   // (2,E) flat
    const int*   atype  = (const int*)d_in[4];
    const int*   mbatch = (const int*)d_in[5];
    float*       out    = (float*)d_out;

    const int E = in_sizes[5];           // mapping_batch element count
    const int* map0 = map;
    const int* map1 = map + E;

    // d_out is re-poisoned before every launch -> zero it first
    zero_out_kernel<<<(out_size + BLK - 1) / BLK, BLK, 0, stream>>>(out, out_size);

    const int nblocks = 2048;
    const int chunk   = (E + nblocks - 1) / nblocks;
    poly_seg_kernel<<<nblocks, BLK, 0, stream>>>(
        pos, ks, v0, map0, map1, atype, mbatch, out, E, chunk);
}

// Round 2
// 191.648 us; speedup vs baseline: 1.4235x; 1.4235x over previous
//
#include <hip/hip_runtime.h>

#define NPAIR 625   // T*T = 25*25
#define GMAX  512   // n_graphs
#define BLK   256

__global__ void zero_out_kernel(float* __restrict__ out, int n) {
    int i = blockIdx.x * blockDim.x + threadIdx.x;
    if (i < n) out[i] = 0.0f;
}

// Pack (pos.x, pos.y, pos.z, bitcast(atype)) into one 16B record per atom.
__global__ void pack_kernel(const float* __restrict__ pos,
                            const int* __restrict__ atype,
                            float4* __restrict__ pos4, int N) {
    int i = blockIdx.x * blockDim.x + threadIdx.x;
    if (i < N) {
        float4 p;
        p.x = pos[i * 3 + 0];
        p.y = pos[i * 3 + 1];
        p.z = pos[i * 3 + 2];
        p.w = __int_as_float(atype[i]);
        pos4[i] = p;
    }
}

__device__ __forceinline__ float edge_V(const float4& a, const float4& b,
                                        const float4* s_k, const float* s_v0) {
    const float dx = a.x - b.x;
    const float dy = a.y - b.y;
    const float dz = a.z - b.z;
    const float x  = sqrtf(dx * dx + dy * dy + dz * dz);
    const int pair = __float_as_int(a.w) * 25 + __float_as_int(b.w);
    const float4 k = s_k[pair];
    return s_v0[pair] + x * (k.x + x * (k.y + x * (k.z + x * k.w)));
}

__global__ __launch_bounds__(BLK) void poly_seg_kernel(
    const float4* __restrict__ pos4,      // (N,4) packed pos+type
    const float*  __restrict__ ks,        // (4,25,25)
    const float*  __restrict__ v0,        // (25,25)
    const int*    __restrict__ map0,      // (E,)
    const int*    __restrict__ map1,      // (E,)
    const int*    __restrict__ mbatch,    // (E,) sorted
    float*        __restrict__ out,       // (G,)
    int E, int gchunk, int aligned1)
{
    __shared__ float4 s_k[NPAIR];
    __shared__ float  s_v0[NPAIR];
    __shared__ float  s_acc[GMAX];

    const int tid = threadIdx.x;

    for (int i = tid; i < NPAIR; i += BLK) {
        s_k[i]  = make_float4(ks[i], ks[NPAIR + i], ks[2 * NPAIR + i], ks[3 * NPAIR + i]);
        s_v0[i] = v0[i];
    }
    for (int i = tid; i < GMAX; i += BLK) s_acc[i] = 0.0f;

    // 4-edge groups, contiguous chunk per block
    const long long g_start64 = (long long)blockIdx.x * (long long)gchunk;
    const long long G4 = ((long long)E + 3) / 4;
    if (g_start64 >= G4) return;                   // block-uniform
    const int g_start = (int)g_start64;
    const int g_end   = (int)min(g_start64 + gchunk, G4);

    __syncthreads();

    float acc  = 0.0f;
    int   gcur = -1;

    for (int g = g_start + tid; g < g_end; g += BLK) {
        const int e0 = g * 4;
        const int n  = min(4, E - e0);

        if (n == 4) {
            const int4 m0 = *(const int4*)(map0 + e0);
            int4 m1;
            if (aligned1) {
                m1 = *(const int4*)(map1 + e0);
            } else {
                m1.x = map1[e0]; m1.y = map1[e0+1]; m1.z = map1[e0+2]; m1.w = map1[e0+3];
            }
            const int4 gb = *(const int4*)(mbatch + e0);

            // issue all 8 gathers before any use (MLP)
            const float4 a0 = pos4[m0.x];
            const float4 a1 = pos4[m0.y];
            const float4 a2 = pos4[m0.z];
            const float4 a3 = pos4[m0.w];
            const float4 b0 = pos4[m1.x];
            const float4 b1 = pos4[m1.y];
            const float4 b2 = pos4[m1.z];
            const float4 b3 = pos4[m1.w];

            const float V0 = edge_V(a0, b0, s_k, s_v0);
            const float V1 = edge_V(a1, b1, s_k, s_v0);
            const float V2 = edge_V(a2, b2, s_k, s_v0);
            const float V3 = edge_V(a3, b3, s_k, s_v0);

            const float Vv[4] = {V0, V1, V2, V3};
            const int   gv[4] = {gb.x, gb.y, gb.z, gb.w};
            #pragma unroll
            for (int j = 0; j < 4; ++j) {
                if (gv[j] != gcur) {
                    if (gcur >= 0) atomicAdd(&s_acc[gcur], acc);
                    gcur = gv[j];
                    acc  = 0.0f;
                }
                acc += Vv[j];
            }
        } else {
            for (int j = 0; j < n; ++j) {
                const int e = e0 + j;
                const float4 a = pos4[map0[e]];
                const float4 b = pos4[map1[e]];
                const float V = edge_V(a, b, s_k, s_v0);
                const int gg = mbatch[e];
                if (gg != gcur) {
                    if (gcur >= 0) atomicAdd(&s_acc[gcur], acc);
                    gcur = gg;
                    acc  = 0.0f;
                }
                acc += V;
            }
        }
    }
    if (gcur >= 0) atomicAdd(&s_acc[gcur], acc);

    __syncthreads();

    // sorted batch => block touched only [blo, bhi]
    const int e_lo = g_start * 4;
    const int e_hi = min(g_end * 4, E) - 1;
    const int blo  = mbatch[e_lo];
    const int bhi  = mbatch[e_hi];
    for (int i = blo + tid; i <= bhi; i += BLK) {
        atomicAdd(&out[i], s_acc[i]);
    }
}

extern "C" void kernel_launch(void* const* d_in, const int* in_sizes, int n_in,
                              void* d_out, int out_size, void* d_ws, size_t ws_size,
                              hipStream_t stream) {
    const float* pos    = (const float*)d_in[0];
    const float* ks     = (const float*)d_in[1];
    const float* v0     = (const float*)d_in[2];
    const int*   map    = (const int*)d_in[3];   // (2,E) flat
    const int*   atype  = (const int*)d_in[4];
    const int*   mbatch = (const int*)d_in[5];
    float*       out    = (float*)d_out;

    const int E = in_sizes[5];
    const int N = in_sizes[0] / 3;
    const int* map0 = map;
    const int* map1 = map + E;

    float4* pos4 = (float4*)d_ws;   // N*16 bytes; ws assumed >= 1.6 MB

    zero_out_kernel<<<(out_size + BLK - 1) / BLK, BLK, 0, stream>>>(out, out_size);
    pack_kernel<<<(N + BLK - 1) / BLK, BLK, 0, stream>>>(pos, atype, pos4, N);

    const int nblocks = 2048;
    const long long G4 = ((long long)E + 3) / 4;
    const int gchunk  = (int)((G4 + nblocks - 1) / nblocks);
    const int aligned1 = ((E & 3) == 0) ? 1 : 0;

    poly_seg_kernel<<<nblocks, BLK, 0, stream>>>(
        pos4, ks, v0, map0, map1, mbatch, out, E, gchunk, aligned1);
}

// Round 3
// 187.171 us; speedup vs baseline: 1.4576x; 1.0239x over previous
//
#include <hip/hip_runtime.h>

#define NPAIR 625   // T*T = 25*25
#define GMAX  512   // n_graphs
#define BLK   256

// Fused: zero the output AND pack (pos.xyz, bitcast(atype)) -> 16B records.
__global__ void pack_zero_kernel(const float* __restrict__ pos,
                                 const int* __restrict__ atype,
                                 float4* __restrict__ pos4, int N,
                                 float* __restrict__ out, int G) {
    int i = blockIdx.x * blockDim.x + threadIdx.x;
    if (i < G) out[i] = 0.0f;
    if (i < N) {
        float4 p;
        p.x = pos[i * 3 + 0];
        p.y = pos[i * 3 + 1];
        p.z = pos[i * 3 + 2];
        p.w = __int_as_float(atype[i]);
        pos4[i] = p;
    }
}

__device__ __forceinline__ float edge_V(const float4& a, const float4& b,
                                        const float4* s_k, const float* s_v0) {
    const float dx = a.x - b.x;
    const float dy = a.y - b.y;
    const float dz = a.z - b.z;
    const float x  = sqrtf(dx * dx + dy * dy + dz * dz);
    const int pair = __float_as_int(a.w) * 25 + __float_as_int(b.w);
    const float4 k = s_k[pair];
    return s_v0[pair] + x * (k.x + x * (k.y + x * (k.z + x * k.w)));
}

__global__ __launch_bounds__(BLK) void poly_seg_kernel(
    const float4* __restrict__ pos4,      // (N,4) packed pos+type
    const float*  __restrict__ ks,        // (4,25,25)
    const float*  __restrict__ v0,        // (25,25)
    const int*    __restrict__ map0,      // (E,)
    const int*    __restrict__ map1,      // (E,)
    const int*    __restrict__ mbatch,    // (E,) sorted
    float*        __restrict__ out,       // (G,)
    int E, int gchunk, int aligned1)
{
    __shared__ float4 s_k[NPAIR];
    __shared__ float  s_v0[NPAIR];
    __shared__ float  s_acc[GMAX];

    const int tid = threadIdx.x;

    for (int i = tid; i < NPAIR; i += BLK) {
        s_k[i]  = make_float4(ks[i], ks[NPAIR + i], ks[2 * NPAIR + i], ks[3 * NPAIR + i]);
        s_v0[i] = v0[i];
    }
    for (int i = tid; i < GMAX; i += BLK) s_acc[i] = 0.0f;

    // 8-edge groups, contiguous chunk per block
    const long long G8 = ((long long)E + 7) / 8;
    const long long g_start64 = (long long)blockIdx.x * (long long)gchunk;
    if (g_start64 >= G8) return;                   // block-uniform
    const int g_start = (int)g_start64;
    const int g_end   = (int)min(g_start64 + gchunk, G8);

    __syncthreads();

    float acc  = 0.0f;
    int   gcur = -1;

    for (int g = g_start + tid; g < g_end; g += BLK) {
        const int e0 = g * 8;

        if (e0 + 8 <= E) {
            const int4 m0a = *(const int4*)(map0 + e0);
            const int4 m0b = *(const int4*)(map0 + e0 + 4);
            int4 m1a, m1b;
            if (aligned1) {
                m1a = *(const int4*)(map1 + e0);
                m1b = *(const int4*)(map1 + e0 + 4);
            } else {
                m1a.x = map1[e0];   m1a.y = map1[e0+1]; m1a.z = map1[e0+2]; m1a.w = map1[e0+3];
                m1b.x = map1[e0+4]; m1b.y = map1[e0+5]; m1b.z = map1[e0+6]; m1b.w = map1[e0+7];
            }
            const int4 gba = *(const int4*)(mbatch + e0);
            const int4 gbb = *(const int4*)(mbatch + e0 + 4);

            // issue all 16 gathers before any use (max MLP)
            const float4 a0 = pos4[m0a.x];
            const float4 a1 = pos4[m0a.y];
            const float4 a2 = pos4[m0a.z];
            const float4 a3 = pos4[m0a.w];
            const float4 a4 = pos4[m0b.x];
            const float4 a5 = pos4[m0b.y];
            const float4 a6 = pos4[m0b.z];
            const float4 a7 = pos4[m0b.w];
            const float4 b0 = pos4[m1a.x];
            const float4 b1 = pos4[m1a.y];
            const float4 b2 = pos4[m1a.z];
            const float4 b3 = pos4[m1a.w];
            const float4 b4 = pos4[m1b.x];
            const float4 b5 = pos4[m1b.y];
            const float4 b6 = pos4[m1b.z];
            const float4 b7 = pos4[m1b.w];

            const float Vv[8] = {
                edge_V(a0, b0, s_k, s_v0), edge_V(a1, b1, s_k, s_v0),
                edge_V(a2, b2, s_k, s_v0), edge_V(a3, b3, s_k, s_v0),
                edge_V(a4, b4, s_k, s_v0), edge_V(a5, b5, s_k, s_v0),
                edge_V(a6, b6, s_k, s_v0), edge_V(a7, b7, s_k, s_v0)
            };
            const int gv[8] = {gba.x, gba.y, gba.z, gba.w,
                               gbb.x, gbb.y, gbb.z, gbb.w};
            #pragma unroll
            for (int j = 0; j < 8; ++j) {
                if (gv[j] != gcur) {
                    if (gcur >= 0) atomicAdd(&s_acc[gcur], acc);
                    gcur = gv[j];
                    acc  = 0.0f;
                }
                acc += Vv[j];
            }
        } else {
            for (int e = e0; e < E; ++e) {
                const float4 a = pos4[map0[e]];
                const float4 b = pos4[map1[e]];
                const float V = edge_V(a, b, s_k, s_v0);
                const int gg = mbatch[e];
                if (gg != gcur) {
                    if (gcur >= 0) atomicAdd(&s_acc[gcur], acc);
                    gcur = gg;
                    acc  = 0.0f;
                }
                acc += V;
            }
        }
    }
    if (gcur >= 0) atomicAdd(&s_acc[gcur], acc);

    __syncthreads();

    // sorted batch => block touched only [blo, bhi]
    const int e_lo = g_start * 8;
    const int e_hi = min((long long)g_end * 8, (long long)E) - 1;
    const int blo  = mbatch[e_lo];
    const int bhi  = mbatch[e_hi];
    for (int i = blo + tid; i <= bhi; i += BLK) {
        atomicAdd(&out[i], s_acc[i]);
    }
}

extern "C" void kernel_launch(void* const* d_in, const int* in_sizes, int n_in,
                              void* d_out, int out_size, void* d_ws, size_t ws_size,
                              hipStream_t stream) {
    const float* pos    = (const float*)d_in[0];
    const float* ks     = (const float*)d_in[1];
    const float* v0     = (const float*)d_in[2];
    const int*   map    = (const int*)d_in[3];   // (2,E) flat
    const int*   atype  = (const int*)d_in[4];
    const int*   mbatch = (const int*)d_in[5];
    float*       out    = (float*)d_out;

    const int E = in_sizes[5];
    const int N = in_sizes[0] / 3;
    const int* map0 = map;
    const int* map1 = map + E;

    float4* pos4 = (float4*)d_ws;   // N*16 bytes

    pack_zero_kernel<<<(N + BLK - 1) / BLK, BLK, 0, stream>>>(
        pos, atype, pos4, N, out, out_size);

    const int nblocks = 2048;
    const long long G8 = ((long long)E + 7) / 8;
    const int gchunk  = (int)((G8 + nblocks - 1) / nblocks);
    const int aligned1 = ((E & 3) == 0) ? 1 : 0;

    poly_seg_kernel<<<nblocks, BLK, 0, stream>>>(
        pos4, ks, v0, map0, map1, mbatch, out, E, gchunk, aligned1);
}

// Round 4
// 182.258 us; speedup vs baseline: 1.4968x; 1.0270x over previous
//
#include <hip/hip_runtime.h>

#define NPAIR 625   // T*T = 25*25
#define GMAX  512   // n_graphs
#define BLK   256

typedef float f32x4 __attribute__((ext_vector_type(4)));

// Fused: zero the output AND pack (pos.xyz, bitcast(atype)) -> 16B records.
__global__ void pack_zero_kernel(const float* __restrict__ pos,
                                 const int* __restrict__ atype,
                                 float4* __restrict__ pos4, int N,
                                 float* __restrict__ out, int G) {
    int i = blockIdx.x * blockDim.x + threadIdx.x;
    if (i < G) out[i] = 0.0f;
    if (i < N) {
        float4 p;
        p.x = pos[i * 3 + 0];
        p.y = pos[i * 3 + 1];
        p.z = pos[i * 3 + 2];
        p.w = __int_as_float(atype[i]);
        pos4[i] = p;
    }
}

__device__ __forceinline__ float edge_V4(const f32x4& a, const f32x4& b,
                                         const float4* s_k, const float* s_v0) {
    const float dx = a.x - b.x;
    const float dy = a.y - b.y;
    const float dz = a.z - b.z;
    const float x  = sqrtf(dx * dx + dy * dy + dz * dz);
    const int pair = __float_as_int(a.w) * 25 + __float_as_int(b.w);
    const float4 k = s_k[pair];
    return s_v0[pair] + x * (k.x + x * (k.y + x * (k.z + x * k.w)));
}

__global__ __launch_bounds__(BLK) void poly_seg_kernel(
    const float*  __restrict__ pos4,      // (N,4) packed pos+type (base for sc0 gathers)
    const float*  __restrict__ ks,        // (4,25,25)
    const float*  __restrict__ v0,        // (25,25)
    const int*    __restrict__ map0,      // (E,)
    const int*    __restrict__ map1,      // (E,)
    const int*    __restrict__ mbatch,    // (E,) sorted
    float*        __restrict__ out,       // (G,)
    int E, int gchunk)
{
    __shared__ float4 s_k[NPAIR];
    __shared__ float  s_v0[NPAIR];
    __shared__ float  s_acc[GMAX];

    const int tid = threadIdx.x;

    for (int i = tid; i < NPAIR; i += BLK) {
        s_k[i]  = make_float4(ks[i], ks[NPAIR + i], ks[2 * NPAIR + i], ks[3 * NPAIR + i]);
        s_v0[i] = v0[i];
    }
    for (int i = tid; i < GMAX; i += BLK) s_acc[i] = 0.0f;

    // 8-edge groups, contiguous chunk per block
    const long long G8 = ((long long)E + 7) / 8;
    const long long g_start64 = (long long)blockIdx.x * (long long)gchunk;
    if (g_start64 >= G8) return;                   // block-uniform
    const int g_start = (int)g_start64;
    const int g_end   = (int)min(g_start64 + gchunk, G8);

    __syncthreads();

    float acc  = 0.0f;
    int   gcur = -1;

    for (int g = g_start + tid; g < g_end; g += BLK) {
        const int e0 = g * 8;

        if (e0 + 8 <= E) {
            const int4 m0a = *(const int4*)(map0 + e0);
            const int4 m0b = *(const int4*)(map0 + e0 + 4);
            const int4 m1a = *(const int4*)(map1 + e0);
            const int4 m1b = *(const int4*)(map1 + e0 + 4);
            const int4 gba = *(const int4*)(mbatch + e0);
            const int4 gbb = *(const int4*)(mbatch + e0 + 4);

            // byte offsets into pos4 (N*16 = 1.6 MB, fits u32)
            const unsigned o0  = (unsigned)m0a.x << 4;
            const unsigned o1  = (unsigned)m0a.y << 4;
            const unsigned o2  = (unsigned)m0a.z << 4;
            const unsigned o3  = (unsigned)m0a.w << 4;
            const unsigned o4  = (unsigned)m0b.x << 4;
            const unsigned o5  = (unsigned)m0b.y << 4;
            const unsigned o6  = (unsigned)m0b.z << 4;
            const unsigned o7  = (unsigned)m0b.w << 4;
            const unsigned o8  = (unsigned)m1a.x << 4;
            const unsigned o9  = (unsigned)m1a.y << 4;
            const unsigned o10 = (unsigned)m1a.z << 4;
            const unsigned o11 = (unsigned)m1a.w << 4;
            const unsigned o12 = (unsigned)m1b.x << 4;
            const unsigned o13 = (unsigned)m1b.y << 4;
            const unsigned o14 = (unsigned)m1b.z << 4;
            const unsigned o15 = (unsigned)m1b.w << 4;

            f32x4 a0, a1, a2, a3, a4, a5, a6, a7;
            f32x4 b0, b1, b2, b3, b4, b5, b6, b7;

            // 16 L1-bypass (sc0) gathers issued back-to-back, one drain.
            asm volatile(
                "global_load_dwordx4 %0, %16, %32 sc0\n\t"
                "global_load_dwordx4 %1, %17, %32 sc0\n\t"
                "global_load_dwordx4 %2, %18, %32 sc0\n\t"
                "global_load_dwordx4 %3, %19, %32 sc0\n\t"
                "global_load_dwordx4 %4, %20, %32 sc0\n\t"
                "global_load_dwordx4 %5, %21, %32 sc0\n\t"
                "global_load_dwordx4 %6, %22, %32 sc0\n\t"
                "global_load_dwordx4 %7, %23, %32 sc0\n\t"
                "global_load_dwordx4 %8, %24, %32 sc0\n\t"
                "global_load_dwordx4 %9, %25, %32 sc0\n\t"
                "global_load_dwordx4 %10, %26, %32 sc0\n\t"
                "global_load_dwordx4 %11, %27, %32 sc0\n\t"
                "global_load_dwordx4 %12, %28, %32 sc0\n\t"
                "global_load_dwordx4 %13, %29, %32 sc0\n\t"
                "global_load_dwordx4 %14, %30, %32 sc0\n\t"
                "global_load_dwordx4 %15, %31, %32 sc0\n\t"
                "s_waitcnt vmcnt(0)"
                : "=&v"(a0), "=&v"(a1), "=&v"(a2), "=&v"(a3),
                  "=&v"(a4), "=&v"(a5), "=&v"(a6), "=&v"(a7),
                  "=&v"(b0), "=&v"(b1), "=&v"(b2), "=&v"(b3),
                  "=&v"(b4), "=&v"(b5), "=&v"(b6), "=&v"(b7)
                : "v"(o0),  "v"(o1),  "v"(o2),  "v"(o3),
                  "v"(o4),  "v"(o5),  "v"(o6),  "v"(o7),
                  "v"(o8),  "v"(o9),  "v"(o10), "v"(o11),
                  "v"(o12), "v"(o13), "v"(o14), "v"(o15),
                  "s"(pos4));

            const float Vv[8] = {
                edge_V4(a0, b0, s_k, s_v0), edge_V4(a1, b1, s_k, s_v0),
                edge_V4(a2, b2, s_k, s_v0), edge_V4(a3, b3, s_k, s_v0),
                edge_V4(a4, b4, s_k, s_v0), edge_V4(a5, b5, s_k, s_v0),
                edge_V4(a6, b6, s_k, s_v0), edge_V4(a7, b7, s_k, s_v0)
            };
            const int gv[8] = {gba.x, gba.y, gba.z, gba.w,
                               gbb.x, gbb.y, gbb.z, gbb.w};
            #pragma unroll
            for (int j = 0; j < 8; ++j) {
                if (gv[j] != gcur) {
                    if (gcur >= 0) atomicAdd(&s_acc[gcur], acc);
                    gcur = gv[j];
                    acc  = 0.0f;
                }
                acc += Vv[j];
            }
        } else {
            const float4* p4 = (const float4*)pos4;
            for (int e = e0; e < E; ++e) {
                const float4 af = p4[map0[e]];
                const float4 bf = p4[map1[e]];
                f32x4 a = {af.x, af.y, af.z, af.w};
                f32x4 b = {bf.x, bf.y, bf.z, bf.w};
                const float V = edge_V4(a, b, s_k, s_v0);
                const int gg = mbatch[e];
                if (gg != gcur) {
                    if (gcur >= 0) atomicAdd(&s_acc[gcur], acc);
                    gcur = gg;
                    acc  = 0.0f;
                }
                acc += V;
            }
        }
    }
    if (gcur >= 0) atomicAdd(&s_acc[gcur], acc);

    __syncthreads();

    // sorted batch => block touched only [blo, bhi]
    const int e_lo = g_start * 8;
    const long long e_hi64 = (long long)g_end * 8;
    const int e_hi = (int)((e_hi64 < (long long)E ? e_hi64 : (long long)E) - 1);
    const int blo  = mbatch[e_lo];
    const int bhi  = mbatch[e_hi];
    for (int i = blo + tid; i <= bhi; i += BLK) {
        atomicAdd(&out[i], s_acc[i]);
    }
}

extern "C" void kernel_launch(void* const* d_in, const int* in_sizes, int n_in,
                              void* d_out, int out_size, void* d_ws, size_t ws_size,
                              hipStream_t stream) {
    const float* pos    = (const float*)d_in[0];
    const float* ks     = (const float*)d_in[1];
    const float* v0     = (const float*)d_in[2];
    const int*   map    = (const int*)d_in[3];   // (2,E) flat
    const int*   atype  = (const int*)d_in[4];
    const int*   mbatch = (const int*)d_in[5];
    float*       out    = (float*)d_out;

    const int E = in_sizes[5];
    const int N = in_sizes[0] / 3;
    const int* map0 = map;
    const int* map1 = map + E;

    float4* pos4 = (float4*)d_ws;   // N*16 bytes

    pack_zero_kernel<<<(N + BLK - 1) / BLK, BLK, 0, stream>>>(
        pos, atype, pos4, N, out, out_size);

    const int nblocks = 2048;
    const long long G8 = ((long long)E + 7) / 8;
    const int gchunk  = (int)((G8 + nblocks - 1) / nblocks);

    poly_seg_kernel<<<nblocks, BLK, 0, stream>>>(
        (const float*)pos4, ks, v0, map0, map1, mbatch, out, E, gchunk);
}